// Round 4
// baseline (11384.105 us; speedup 1.0000x reference)
//
#include <hip/hip_runtime.h>

// NConv depth-completion net, fp32. R4:
// - 2-px/thread x-blocking (32x16 tile), LDS taps read as aligned float2 (b64)
// - bank-uniform LDS row strides (40 for 5x5 tiles, 36/24 for 3x3)
// - decoder upsampled source staged at native half-res (cat LDS 41.5->29.6KB)
// - wave-0 parallel weight-sum reduction
// - NO __launch_bounds__ minwaves (R2: spill->scratch traffic 32x blowup)

#define EPSN 1e-20f

__device__ __forceinline__ float softplusf(float x) {
    // matches jax.nn.softplus = max(x,0) + log1p(exp(-|x|))
    return fmaxf(x, 0.f) + log1pf(expf(-fabsf(x)));
}
__device__ __forceinline__ float rcpf(float x) { return __builtin_amdgcn_rcpf(x); }

// Sum s_w4[0..n) across wave 0; lane 0 writes *dst. Needs __syncthreads after.
__device__ __forceinline__ void wsum4(const float4* s_w4, int n, int tid, float4* dst)
{
    if (tid < 64) {
        float4 a = make_float4(0.f, 0.f, 0.f, 0.f);
        for (int i = tid; i < n; i += 64) {
            float4 w = s_w4[i];
            a.x += w.x; a.y += w.y; a.z += w.z; a.w += w.w;
        }
        #pragma unroll
        for (int off = 32; off; off >>= 1) {
            a.x += __shfl_xor(a.x, off);
            a.y += __shfl_xor(a.y, off);
            a.z += __shfl_xor(a.z, off);
            a.w += __shfl_xor(a.w, off);
        }
        if (tid == 0) *dst = a;
    }
}

// 8 FMAs into the two-pixel accumulators for one weight float4.
#define NC_ACC(W, XA, CA, XB, CB)                                   \
    nA[0]=fmaf((W).x,(XA),nA[0]); dA[0]=fmaf((W).x,(CA),dA[0]);     \
    nA[1]=fmaf((W).y,(XA),nA[1]); dA[1]=fmaf((W).y,(CA),dA[1]);     \
    nA[2]=fmaf((W).z,(XA),nA[2]); dA[2]=fmaf((W).z,(CA),dA[2]);     \
    nA[3]=fmaf((W).w,(XA),nA[3]); dA[3]=fmaf((W).w,(CA),dA[3]);     \
    nB[0]=fmaf((W).x,(XB),nB[0]); dB[0]=fmaf((W).x,(CB),dB[0]);     \
    nB[1]=fmaf((W).y,(XB),nB[1]); dB[1]=fmaf((W).y,(CB),dB[1]);     \
    nB[2]=fmaf((W).z,(XB),nB[2]); dB[2]=fmaf((W).z,(CB),dB[2]);     \
    nB[3]=fmaf((W).w,(XB),nB[3]); dB[3]=fmaf((W).w,(CB),dB[3]);

// Shared epilogue: divide, bias, dual-pixel float2 store.
#define NC_STORE(PLANE, HOUT, WOUT)                                               \
    {                                                                             \
        const int oh = oh0 + ty, ow = ow0 + 2 * tx;                               \
        if (oh < (HOUT) && ow < (WOUT)) {                                         \
            float4 bias = s_bias, ssum = s_sum;                                   \
            float rs[4] = {rcpf(ssum.x), rcpf(ssum.y), rcpf(ssum.z), rcpf(ssum.w)};\
            float bb[4] = {bias.x, bias.y, bias.z, bias.w};                       \
            size_t ob = ((size_t)(b * 4)) * (PLANE) + (size_t)oh * (WOUT) + ow;   \
            bool two = (ow + 1 < (WOUT));                                         \
            _Pragma("unroll")                                                     \
            for (int co = 0; co < 4; ++co) {                                      \
                float x0 = nA[co] * rcpf(dA[co] + EPSN) + bb[co];                 \
                float c0 = dA[co] * rs[co];                                       \
                if (two) {                                                        \
                    float2 vx = make_float2(x0, nB[co] * rcpf(dB[co] + EPSN) + bb[co]); \
                    float2 vc = make_float2(c0, dB[co] * rs[co]);                 \
                    *(float2*)&xout[ob + co * (PLANE)] = vx;                      \
                    *(float2*)&cout[ob + co * (PLANE)] = vc;                      \
                } else {                                                          \
                    xout[ob + co * (PLANE)] = x0;                                 \
                    cout[ob + co * (PLANE)] = c0;                                 \
                }                                                                 \
            }                                                                     \
        }                                                                         \
    }

// ---------------------------------------------------------------------------
// 5x5 normalized conv, pad=2, CO=4. Tile 32x16, 2 px/thread.
// ---------------------------------------------------------------------------
template<int CI, bool FIRST>
__global__ __launch_bounds__(256) void nconv5(
    const float* __restrict__ xin, const float* __restrict__ cin,
    const float* __restrict__ wraw, const float* __restrict__ braw,
    float* __restrict__ xout, float* __restrict__ cout,
    int Hh, int Ww)
{
    const int LTH = 20, LTW = 36, SW = 40;     // 16+4 rows, 32+4 cols, stride 40
    __shared__ float s_c [CI][LTH][SW];
    __shared__ float s_xc[CI][LTH][SW];
    __shared__ float4 s_w4[CI * 25];
    __shared__ float4 s_sum, s_bias;

    const int b   = blockIdx.z;
    const int oh0 = blockIdx.y * 16, ow0 = blockIdx.x * 32;
    const int tx = threadIdx.x, ty = threadIdx.y;
    const int tid = ty * 16 + tx;

    if (tid < CI * 25) {
        float4 w;
        w.x = softplusf(wraw[0 * CI * 25 + tid]);
        w.y = softplusf(wraw[1 * CI * 25 + tid]);
        w.z = softplusf(wraw[2 * CI * 25 + tid]);
        w.w = softplusf(wraw[3 * CI * 25 + tid]);
        s_w4[tid] = w;
    }
    if (tid == 0) s_bias = make_float4(braw[0], braw[1], braw[2], braw[3]);
    __syncthreads();

    const size_t plane = (size_t)Hh * Ww;
    for (int i = tid; i < LTH * LTW; i += 256) {
        int ly = i / LTW, lx = i - ly * LTW;
        int ih = oh0 - 2 + ly, iw = ow0 - 2 + lx;
        bool ok = (ih >= 0) & (ih < Hh) & (iw >= 0) & (iw < Ww);
        #pragma unroll
        for (int ci = 0; ci < CI; ++ci) {
            float x = 0.f, c = 0.f;
            if (ok) {
                size_t idx = ((size_t)(b * CI + ci)) * plane + (size_t)ih * Ww + iw;
                x = xin[idx];
                c = FIRST ? ((x > 0.01f) ? 1.f : 0.f) : cin[idx];
            }
            s_c [ci][ly][lx] = c;
            s_xc[ci][ly][lx] = x * c;
        }
    }
    wsum4(s_w4, CI * 25, tid, &s_sum);
    __syncthreads();

    float nA[4] = {}, dA[4] = {}, nB[4] = {}, dB[4] = {};
    #pragma unroll
    for (int ci = 0; ci < CI; ++ci)
    #pragma unroll
    for (int kj = 0; kj < 5; ++kj) {
        const float2* rc = (const float2*)&s_c [ci][ty + kj][0];
        const float2* rx = (const float2*)&s_xc[ci][ty + kj][0];
        float2 c0 = rc[tx], c1 = rc[tx + 1], c2 = rc[tx + 2];
        float2 x0 = rx[tx], x1 = rx[tx + 1], x2 = rx[tx + 2];
        float cv[6] = {c0.x, c0.y, c1.x, c1.y, c2.x, c2.y};
        float xv[6] = {x0.x, x0.y, x1.x, x1.y, x2.x, x2.y};
        #pragma unroll
        for (int ki = 0; ki < 5; ++ki) {
            float4 w = s_w4[ci * 25 + kj * 5 + ki];
            NC_ACC(w, xv[ki], cv[ki], xv[ki + 1], cv[ki + 1])
        }
    }
    NC_STORE(plane, Hh, Ww)
}

// ---------------------------------------------------------------------------
// 2x2 pool: argmax of confidence (first-max tie rule), gather x, c = max/4.
// ---------------------------------------------------------------------------
__global__ __launch_bounds__(256) void pool2k(
    const float* __restrict__ x, const float* __restrict__ c,
    float* __restrict__ xo, float* __restrict__ co, int Hh, int Ww)
{
    int H2 = Hh / 2, W2 = Ww / 2;
    int total = 8 * 4 * H2 * W2;
    int i = blockIdx.x * 256 + threadIdx.x;
    if (i >= total) return;
    int ow = i % W2;
    int oh = (i / W2) % H2;
    int ch = (i / (W2 * H2)) % 4;
    int b  =  i / (W2 * H2 * 4);
    size_t base = (((size_t)(b * 4 + ch)) * Hh + 2 * oh) * Ww + 2 * ow;
    float c00 = c[base], c01 = c[base + 1], c10 = c[base + Ww], c11 = c[base + Ww + 1];
    int k = 0; float cm = c00;
    if (c01 > cm) { cm = c01; k = 1; }
    if (c10 > cm) { cm = c10; k = 2; }
    if (c11 > cm) { cm = c11; k = 3; }
    float xv = (k == 0) ? x[base] : (k == 1) ? x[base + 1] : (k == 2) ? x[base + Ww] : x[base + Ww + 1];
    size_t ob = (((size_t)(b * 4 + ch)) * H2 + oh) * W2 + ow;
    xo[ob] = xv;
    co[ob] = cm * 0.25f;
}

// ---------------------------------------------------------------------------
// 3x3 normalized conv over concat{direct 4ch (Hin,Win), nearest-2x-up 4ch
// (Hin/2,Win/2)}. Up source staged at NATIVE half resolution. Tile 32x16.
// UP_FIRST: up occupies weight channels 0-3 (w6) else 4-7 (w4,w5).
// ---------------------------------------------------------------------------
template<bool UP_FIRST, int PAD>
__global__ __launch_bounds__(256) void nconv3cat(
    const float* __restrict__ xd, const float* __restrict__ cd,
    const float* __restrict__ xu, const float* __restrict__ cu,
    const float* __restrict__ wraw, const float* __restrict__ braw,
    float* __restrict__ xout, float* __restrict__ cout,
    int Hin, int Win)
{
    const int LTH = 18, LTW = 34, SW = 36;   // direct: 16+2 rows, 32+2 cols
    const int LUH = 10, LUW = 18, SU = 24;   // up, native half-res
    __shared__ float s_cd[4][LTH][SW], s_xd[4][LTH][SW];
    __shared__ float s_cu[4][LUH][SU], s_xu[4][LUH][SU];
    __shared__ float4 s_w4[72];
    __shared__ float4 s_sum, s_bias;

    const int Hout = Hin - 2 + 2 * PAD, Wout = Win - 2 + 2 * PAD;
    const int Hu = Hin / 2, Wu = Win / 2;
    const int b   = blockIdx.z;
    const int oh0 = blockIdx.y * 16, ow0 = blockIdx.x * 32;
    const int tx = threadIdx.x, ty = threadIdx.y;
    const int tid = ty * 16 + tx;

    if (tid < 72) {
        float4 w;
        w.x = softplusf(wraw[0 * 72 + tid]);
        w.y = softplusf(wraw[1 * 72 + tid]);
        w.z = softplusf(wraw[2 * 72 + tid]);
        w.w = softplusf(wraw[3 * 72 + tid]);
        s_w4[tid] = w;
    }
    if (tid == 0) s_bias = make_float4(braw[0], braw[1], braw[2], braw[3]);
    __syncthreads();

    const size_t planeD = (size_t)Hin * Win, planeU = (size_t)Hu * Wu;
    for (int i = tid; i < LTH * LTW; i += 256) {
        int ly = i / LTW, lx = i - ly * LTW;
        int ih = oh0 - PAD + ly, iw = ow0 - PAD + lx;
        bool ok = (ih >= 0) & (ih < Hin) & (iw >= 0) & (iw < Win);
        #pragma unroll
        for (int ci = 0; ci < 4; ++ci) {
            float x = 0.f, c = 0.f;
            if (ok) {
                size_t idx = ((size_t)(b * 4 + ci)) * planeD + (size_t)ih * Win + iw;
                x = xd[idx]; c = cd[idx];
            }
            s_cd[ci][ly][lx] = c;
            s_xd[ci][ly][lx] = x * c;
        }
    }
    const int ru0 = (oh0 - PAD) >> 1, cu0 = (ow0 - PAD) >> 1;
    for (int i = tid; i < LUH * LUW; i += 256) {
        int ly = i / LUW, lx = i - ly * LUW;
        int ur = ru0 + ly, uc = cu0 + lx;
        bool ok = (ur >= 0) & (ur < Hu) & (uc >= 0) & (uc < Wu);
        #pragma unroll
        for (int ci = 0; ci < 4; ++ci) {
            float x = 0.f, c = 0.f;
            if (ok) {
                size_t idx = ((size_t)(b * 4 + ci)) * planeU + (size_t)ur * Wu + uc;
                x = xu[idx]; c = cu[idx];
            }
            s_cu[ci][ly][lx] = c;
            s_xu[ci][ly][lx] = x * c;
        }
    }
    wsum4(s_w4, 72, tid, &s_sum);
    __syncthreads();

    float nA[4] = {}, dA[4] = {}, nB[4] = {}, dB[4] = {};
    #pragma unroll
    for (int ci = 0; ci < 4; ++ci) {
        const int chD = UP_FIRST ? ci + 4 : ci;
        const int chU = UP_FIRST ? ci : ci + 4;
        #pragma unroll
        for (int kj = 0; kj < 3; ++kj) {
            // direct source taps: staged cols 2tx .. 2tx+3 (two aligned float2)
            const float2* rc = (const float2*)&s_cd[ci][ty + kj][0];
            const float2* rx = (const float2*)&s_xd[ci][ty + kj][0];
            float2 c0 = rc[tx], c1 = rc[tx + 1];
            float2 x0 = rx[tx], x1 = rx[tx + 1];
            float cv[4] = {c0.x, c0.y, c1.x, c1.y};
            float xv[4] = {x0.x, x0.y, x1.x, x1.y};
            #pragma unroll
            for (int ki = 0; ki < 3; ++ki) {
                float4 w = s_w4[chD * 9 + kj * 3 + ki];
                NC_ACC(w, xv[ki], cv[ki], xv[ki + 1], cv[ki + 1])
            }
            // up source: staged half-res row (ty+kj+PAD)>>1, tap m -> col tx+((m+PAD)>>1)
            int lyu = (ty + kj + PAD) >> 1;
            const float* urc = &s_cu[ci][lyu][0];
            const float* urx = &s_xu[ci][lyu][0];
            float ucv[4], uxv[4];
            if (PAD == 1) {
                float a0 = urc[tx], a1 = urc[tx + 1], a2 = urc[tx + 2];
                float e0 = urx[tx], e1 = urx[tx + 1], e2 = urx[tx + 2];
                ucv[0] = a0; ucv[1] = a1; ucv[2] = a1; ucv[3] = a2;
                uxv[0] = e0; uxv[1] = e1; uxv[2] = e1; uxv[3] = e2;
            } else {
                float a0 = urc[tx], a1 = urc[tx + 1];
                float e0 = urx[tx], e1 = urx[tx + 1];
                ucv[0] = a0; ucv[1] = a0; ucv[2] = a1; ucv[3] = a1;
                uxv[0] = e0; uxv[1] = e0; uxv[2] = e1; uxv[3] = e1;
            }
            #pragma unroll
            for (int ki = 0; ki < 3; ++ki) {
                float4 w = s_w4[chU * 9 + kj * 3 + ki];
                NC_ACC(w, uxv[ki], ucv[ki], uxv[ki + 1], ucv[ki + 1])
            }
        }
    }
    size_t planeO = (size_t)Hout * Wout;
    NC_STORE(planeO, Hout, Wout)
}

// ---------------------------------------------------------------------------
// 3x3 normalized conv, 4->4, pad=1 (w65). Tile 32x16, 2 px/thread.
// ---------------------------------------------------------------------------
__global__ __launch_bounds__(256) void nconv3p(
    const float* __restrict__ xin, const float* __restrict__ cin,
    const float* __restrict__ wraw, const float* __restrict__ braw,
    float* __restrict__ xout, float* __restrict__ cout,
    int Hh, int Ww)
{
    const int LTH = 18, LTW = 34, SW = 36;
    __shared__ float s_c [4][LTH][SW];
    __shared__ float s_xc[4][LTH][SW];
    __shared__ float4 s_w4[36];
    __shared__ float4 s_sum, s_bias;

    const int b   = blockIdx.z;
    const int oh0 = blockIdx.y * 16, ow0 = blockIdx.x * 32;
    const int tx = threadIdx.x, ty = threadIdx.y;
    const int tid = ty * 16 + tx;

    if (tid < 36) {
        float4 w;
        w.x = softplusf(wraw[0 * 36 + tid]);
        w.y = softplusf(wraw[1 * 36 + tid]);
        w.z = softplusf(wraw[2 * 36 + tid]);
        w.w = softplusf(wraw[3 * 36 + tid]);
        s_w4[tid] = w;
    }
    if (tid == 0) s_bias = make_float4(braw[0], braw[1], braw[2], braw[3]);
    __syncthreads();

    const size_t plane = (size_t)Hh * Ww;
    for (int i = tid; i < LTH * LTW; i += 256) {
        int ly = i / LTW, lx = i - ly * LTW;
        int ih = oh0 - 1 + ly, iw = ow0 - 1 + lx;
        bool ok = (ih >= 0) & (ih < Hh) & (iw >= 0) & (iw < Ww);
        #pragma unroll
        for (int ci = 0; ci < 4; ++ci) {
            float x = 0.f, c = 0.f;
            if (ok) {
                size_t idx = ((size_t)(b * 4 + ci)) * plane + (size_t)ih * Ww + iw;
                x = xin[idx]; c = cin[idx];
            }
            s_c [ci][ly][lx] = c;
            s_xc[ci][ly][lx] = x * c;
        }
    }
    wsum4(s_w4, 36, tid, &s_sum);
    __syncthreads();

    float nA[4] = {}, dA[4] = {}, nB[4] = {}, dB[4] = {};
    #pragma unroll
    for (int ci = 0; ci < 4; ++ci)
    #pragma unroll
    for (int kj = 0; kj < 3; ++kj) {
        const float2* rc = (const float2*)&s_c [ci][ty + kj][0];
        const float2* rx = (const float2*)&s_xc[ci][ty + kj][0];
        float2 c0 = rc[tx], c1 = rc[tx + 1];
        float2 x0 = rx[tx], x1 = rx[tx + 1];
        float cv[4] = {c0.x, c0.y, c1.x, c1.y};
        float xv[4] = {x0.x, x0.y, x1.x, x1.y};
        #pragma unroll
        for (int ki = 0; ki < 3; ++ki) {
            float4 w = s_w4[ci * 9 + kj * 3 + ki];
            NC_ACC(w, xv[ki], cv[ki], xv[ki + 1], cv[ki + 1])
        }
    }
    NC_STORE(plane, Hh, Ww)
}

// ---------------------------------------------------------------------------
// Fused: 1x1 nconv 4->1 (w7) on (478,638) + adaptive avg pool -> (480,640).
// ---------------------------------------------------------------------------
__global__ __launch_bounds__(256) void finalk(
    const float* __restrict__ x, const float* __restrict__ c,
    const float* __restrict__ w7, const float* __restrict__ b7,
    float* __restrict__ out)
{
    __shared__ float sw[5];
    if (threadIdx.x < 4) sw[threadIdx.x] = softplusf(w7[threadIdx.x]);
    if (threadIdx.x == 4) sw[4] = b7[0];
    __syncthreads();

    const int HI = 478, WI = 638, HO = 480, WO = 640;
    int total = 8 * HO * WO;
    int i = blockIdx.x * 256 + threadIdx.x;
    if (i >= total) return;
    int ow = i % WO;
    int oh = (i / WO) % HO;
    int b  = i / (WO * HO);
    float w0 = sw[0], w1 = sw[1], w2 = sw[2], w3 = sw[3], bias = sw[4];

    int sh = (oh * HI) / HO, eh = ((oh + 1) * HI + HO - 1) / HO;
    int sw_ = (ow * WI) / WO, ew = ((ow + 1) * WI + WO - 1) / WO;
    const size_t plane = (size_t)HI * WI;
    float s = 0.f;
    for (int ih = sh; ih < eh; ++ih)
        for (int iw = sw_; iw < ew; ++iw) {
            size_t base = (size_t)b * 4 * plane + (size_t)ih * WI + iw;
            float cc0 = c[base + 0 * plane], cc1 = c[base + 1 * plane],
                  cc2 = c[base + 2 * plane], cc3 = c[base + 3 * plane];
            float nom = w0 * x[base + 0 * plane] * cc0 + w1 * x[base + 1 * plane] * cc1
                      + w2 * x[base + 2 * plane] * cc2 + w3 * x[base + 3 * plane] * cc3;
            float den = w0 * cc0 + w1 * cc1 + w2 * cc2 + w3 * cc3;
            s += nom * rcpf(den + EPSN) + bias;
        }
    out[i] = s * rcpf((float)((eh - sh) * (ew - sw_)));
}

// ---------------------------------------------------------------------------
extern "C" void kernel_launch(void* const* d_in, const int* in_sizes, int n_in,
                              void* d_out, int out_size, void* d_ws, size_t ws_size,
                              hipStream_t stream)
{
    const float* S   = (const float*)d_in[1];
    const float* w1  = (const float*)d_in[3];  const float* b1  = (const float*)d_in[4];
    const float* w2  = (const float*)d_in[5];  const float* b2  = (const float*)d_in[6];
    const float* w3  = (const float*)d_in[7];  const float* b3  = (const float*)d_in[8];
    const float* w4  = (const float*)d_in[9];  const float* b4  = (const float*)d_in[10];
    const float* w5  = (const float*)d_in[11]; const float* b5  = (const float*)d_in[12];
    const float* w6  = (const float*)d_in[13]; const float* b6  = (const float*)d_in[14];
    const float* w65 = (const float*)d_in[15]; const float* b65 = (const float*)d_in[16];
    const float* w7  = (const float*)d_in[17]; const float* b7  = (const float*)d_in[18];
    float* out = (float*)d_out;
    float* ws  = (float*)d_ws;

    const size_t FULL = 9830400, HALF = 2457600, QUAR = 614400, EIGH = 153600;
    float *A0 = ws,        *A1 = A0 + FULL, *A2 = A1 + FULL, *A3 = A2 + FULL;
    float *P0 = A3 + FULL, *P1 = P0 + HALF, *P2 = P1 + HALF, *P3 = P2 + HALF;
    float *Q0 = P3 + HALF, *Q1 = Q0 + QUAR, *Q2 = Q1 + QUAR, *Q3 = Q2 + QUAR;
    float *E0 = Q3 + QUAR, *E1 = E0 + EIGH, *E2 = E1 + EIGH, *E3 = E2 + EIGH;

    dim3 blk(16, 16);
    auto grd = [](int Ho, int Wo) { return dim3((Wo + 31) / 32, (Ho + 15) / 16, 8); };

    // encoder, full res
    nconv5<1, true ><<<grd(480, 640), blk, 0, stream>>>(S,  S,  w1, b1, A0, A1, 480, 640);
    nconv5<4, false><<<grd(480, 640), blk, 0, stream>>>(A0, A1, w2, b2, A2, A3, 480, 640);
    nconv5<4, false><<<grd(480, 640), blk, 0, stream>>>(A2, A3, w3, b3, A0, A1, 480, 640);
    // 1/2 scale
    pool2k<<<(8 * 4 * 240 * 320 + 255) / 256, 256, 0, stream>>>(A0, A1, P0, P1, 480, 640);
    nconv5<4, false><<<grd(240, 320), blk, 0, stream>>>(P0, P1, w2, b2, P2, P3, 240, 320);
    nconv5<4, false><<<grd(240, 320), blk, 0, stream>>>(P2, P3, w3, b3, P0, P1, 240, 320); // x2_ds
    // 1/4 scale
    pool2k<<<(8 * 4 * 120 * 160 + 255) / 256, 256, 0, stream>>>(P0, P1, Q0, Q1, 240, 320);
    nconv5<4, false><<<grd(120, 160), blk, 0, stream>>>(Q0, Q1, w2, b2, Q2, Q3, 120, 160); // x3_ds
    // 1/8 scale
    pool2k<<<(8 * 4 * 60 * 80 + 255) / 256, 256, 0, stream>>>(Q2, Q3, E0, E1, 120, 160);
    nconv5<4, false><<<grd(60, 80), blk, 0, stream>>>(E0, E1, w2, b2, E2, E3, 60, 80);     // x4_ds
    // decoder
    nconv3cat<false, 1><<<grd(120, 160), blk, 0, stream>>>(Q2, Q3, E2, E3, w4, b4, Q0, Q1, 120, 160);
    nconv3cat<false, 1><<<grd(240, 320), blk, 0, stream>>>(P0, P1, Q0, Q1, w5, b5, P2, P3, 240, 320);
    nconv3cat<true , 0><<<grd(478, 638), blk, 0, stream>>>(A0, A1, P2, P3, w6, b6, A2, A3, 480, 640);
    nconv3p<<<grd(478, 638), blk, 0, stream>>>(A2, A3, w65, b65, A0, A1, 478, 638);
    finalk<<<(8 * 480 * 640 + 255) / 256, 256, 0, stream>>>(A0, A1, w7, b7, out);
}

// Round 5
// 552.775 us; speedup vs baseline: 20.5945x; 20.5945x over previous
//
#include <hip/hip_runtime.h>

// NConv depth-completion net, fp32. R5 = R3 +:
// - LDS staged as interleaved float2(c, x*c) -> one ds_read_b64 per tap
//   (R2 measured 0 bank conflicts for this layout; R3's scalar pair cost 1.25e7)
// - #pragma unroll 1 on the ci loop: bounds load-hoisting scope (R4: full
//   unroll -> 256 VGPR + 9.6GB scratch traffic). No launch_bounds minwaves
//   (R2: forced 64-VGPR cap -> spills).

#define EPSN 1e-20f

__device__ __forceinline__ float softplusf(float x) {
    // matches jax.nn.softplus = max(x,0) + log1p(exp(-|x|))
    return fmaxf(x, 0.f) + log1pf(expf(-fabsf(x)));
}
__device__ __forceinline__ float rcpf(float x) { return __builtin_amdgcn_rcpf(x); }

// Sum s_w4[0..n) across wave 0; lane 0 writes *dst. Needs __syncthreads after.
__device__ __forceinline__ void wsum4(const float4* s_w4, int n, int tid, float4* dst)
{
    if (tid < 64) {
        float4 a = make_float4(0.f, 0.f, 0.f, 0.f);
        for (int i = tid; i < n; i += 64) {
            float4 w = s_w4[i];
            a.x += w.x; a.y += w.y; a.z += w.z; a.w += w.w;
        }
        #pragma unroll
        for (int off = 32; off; off >>= 1) {
            a.x += __shfl_xor(a.x, off);
            a.y += __shfl_xor(a.y, off);
            a.z += __shfl_xor(a.z, off);
            a.w += __shfl_xor(a.w, off);
        }
        if (tid == 0) *dst = a;
    }
}

// 8 FMAs: one float2(c,xc) tap against a float4 out-channel weight pack.
#define NC_TAP(W, V)                                              \
    nom[0] = fmaf((W).x, (V).y, nom[0]); den[0] = fmaf((W).x, (V).x, den[0]); \
    nom[1] = fmaf((W).y, (V).y, nom[1]); den[1] = fmaf((W).y, (V).x, den[1]); \
    nom[2] = fmaf((W).z, (V).y, nom[2]); den[2] = fmaf((W).z, (V).x, den[2]); \
    nom[3] = fmaf((W).w, (V).y, nom[3]); den[3] = fmaf((W).w, (V).x, den[3]);

#define NC_EPILOGUE(PLANE, WOUT)                                       \
    {                                                                  \
        float4 bias = s_bias, ssum = s_sum;                            \
        size_t ob = ((size_t)(b * 4)) * (PLANE) + (size_t)oh * (WOUT) + ow; \
        xout[ob + 0 * (PLANE)] = nom[0] * rcpf(den[0] + EPSN) + bias.x; \
        xout[ob + 1 * (PLANE)] = nom[1] * rcpf(den[1] + EPSN) + bias.y; \
        xout[ob + 2 * (PLANE)] = nom[2] * rcpf(den[2] + EPSN) + bias.z; \
        xout[ob + 3 * (PLANE)] = nom[3] * rcpf(den[3] + EPSN) + bias.w; \
        cout[ob + 0 * (PLANE)] = den[0] * rcpf(ssum.x);                \
        cout[ob + 1 * (PLANE)] = den[1] * rcpf(ssum.y);                \
        cout[ob + 2 * (PLANE)] = den[2] * rcpf(ssum.z);                \
        cout[ob + 3 * (PLANE)] = den[3] * rcpf(ssum.w);                \
    }

// ---------------------------------------------------------------------------
// 5x5 normalized conv, pad=2, CO=4. 16x16 tile + halo 2. 1 px/thread.
// ---------------------------------------------------------------------------
template<int CI, bool FIRST>
__global__ __launch_bounds__(256) void nconv5(
    const float* __restrict__ xin, const float* __restrict__ cin,
    const float* __restrict__ wraw, const float* __restrict__ braw,
    float* __restrict__ xout, float* __restrict__ cout,
    int Hh, int Ww)
{
    const int LT = 20;                                 // 16+4
    __shared__ float2 sd[CI][LT][LT + 1];              // (c, x*c)
    __shared__ float4 s_w4[CI * 25];
    __shared__ float4 s_sum, s_bias;

    const int b   = blockIdx.z;
    const int oh0 = blockIdx.y * 16, ow0 = blockIdx.x * 16;
    const int tid = threadIdx.y * 16 + threadIdx.x;

    if (tid < CI * 25) {
        float4 w;
        w.x = softplusf(wraw[0 * CI * 25 + tid]);
        w.y = softplusf(wraw[1 * CI * 25 + tid]);
        w.z = softplusf(wraw[2 * CI * 25 + tid]);
        w.w = softplusf(wraw[3 * CI * 25 + tid]);
        s_w4[tid] = w;
    }
    if (tid == 0) s_bias = make_float4(braw[0], braw[1], braw[2], braw[3]);
    __syncthreads();

    const size_t plane = (size_t)Hh * Ww;
    for (int i = tid; i < LT * LT; i += 256) {
        int ly = i / LT, lx = i - ly * LT;
        int ih = oh0 - 2 + ly, iw = ow0 - 2 + lx;
        bool ok = (ih >= 0) & (ih < Hh) & (iw >= 0) & (iw < Ww);
        #pragma unroll
        for (int ci = 0; ci < CI; ++ci) {
            float x = 0.f, c = 0.f;
            if (ok) {
                size_t idx = ((size_t)(b * CI + ci)) * plane + (size_t)ih * Ww + iw;
                x = xin[idx];
                c = FIRST ? ((x > 0.01f) ? 1.f : 0.f) : cin[idx];
            }
            sd[ci][ly][lx] = make_float2(c, x * c);
        }
    }
    wsum4(s_w4, CI * 25, tid, &s_sum);
    __syncthreads();

    const int oh = oh0 + threadIdx.y, ow = ow0 + threadIdx.x;
    if (oh >= Hh || ow >= Ww) return;
    const int ty = threadIdx.y, tx = threadIdx.x;

    float nom[4] = {}, den[4] = {};
    #pragma unroll 1
    for (int ci = 0; ci < CI; ++ci) {
        #pragma unroll
        for (int kj = 0; kj < 5; ++kj)
        #pragma unroll
        for (int ki = 0; ki < 5; ++ki) {
            float2 v = sd[ci][ty + kj][tx + ki];
            float4 w = s_w4[ci * 25 + kj * 5 + ki];
            NC_TAP(w, v)
        }
    }
    NC_EPILOGUE(plane, Ww)
}

// ---------------------------------------------------------------------------
// 2x2 pool: argmax of confidence (first-max tie rule), gather x, c = max/4.
// ---------------------------------------------------------------------------
__global__ __launch_bounds__(256) void pool2k(
    const float* __restrict__ x, const float* __restrict__ c,
    float* __restrict__ xo, float* __restrict__ co, int Hh, int Ww)
{
    int H2 = Hh / 2, W2 = Ww / 2;
    int total = 8 * 4 * H2 * W2;
    int i = blockIdx.x * 256 + threadIdx.x;
    if (i >= total) return;
    int ow = i % W2;
    int oh = (i / W2) % H2;
    int ch = (i / (W2 * H2)) % 4;
    int b  =  i / (W2 * H2 * 4);
    size_t base = (((size_t)(b * 4 + ch)) * Hh + 2 * oh) * Ww + 2 * ow;
    float c00 = c[base], c01 = c[base + 1], c10 = c[base + Ww], c11 = c[base + Ww + 1];
    int k = 0; float cm = c00;
    if (c01 > cm) { cm = c01; k = 1; }
    if (c10 > cm) { cm = c10; k = 2; }
    if (c11 > cm) { cm = c11; k = 3; }
    float xv = (k == 0) ? x[base] : (k == 1) ? x[base + 1] : (k == 2) ? x[base + Ww] : x[base + Ww + 1];
    size_t ob = (((size_t)(b * 4 + ch)) * H2 + oh) * W2 + ow;
    xo[ob] = xv;
    co[ob] = cm * 0.25f;
}

// ---------------------------------------------------------------------------
// 3x3 normalized conv over concat{direct 4ch (Hin,Win), nearest-2x-up 4ch}.
// Up source staged expanded (R3-proven). UP_FIRST: up in channels 0-3 (w6).
// ---------------------------------------------------------------------------
template<bool UP_FIRST, int PAD>
__global__ __launch_bounds__(256) void nconv3cat(
    const float* __restrict__ xd, const float* __restrict__ cd,
    const float* __restrict__ xu, const float* __restrict__ cu,
    const float* __restrict__ wraw, const float* __restrict__ braw,
    float* __restrict__ xout, float* __restrict__ cout,
    int Hin, int Win)
{
    const int LT = 18;                               // 16+2
    __shared__ float2 sd[8][LT][LT + 1];
    __shared__ float4 s_w4[72];
    __shared__ float4 s_sum, s_bias;

    const int Hout = Hin - 2 + 2 * PAD, Wout = Win - 2 + 2 * PAD;
    const int b   = blockIdx.z;
    const int oh0 = blockIdx.y * 16, ow0 = blockIdx.x * 16;
    const int tid = threadIdx.y * 16 + threadIdx.x;

    if (tid < 72) {
        float4 w;
        w.x = softplusf(wraw[0 * 72 + tid]);
        w.y = softplusf(wraw[1 * 72 + tid]);
        w.z = softplusf(wraw[2 * 72 + tid]);
        w.w = softplusf(wraw[3 * 72 + tid]);
        s_w4[tid] = w;
    }
    if (tid == 0) s_bias = make_float4(braw[0], braw[1], braw[2], braw[3]);
    __syncthreads();

    const int Hu = Hin / 2, Wu = Win / 2;
    const size_t planeD = (size_t)Hin * Win, planeU = (size_t)Hu * Wu;
    for (int i = tid; i < LT * LT; i += 256) {
        int ly = i / LT, lx = i - ly * LT;
        int ih = oh0 - PAD + ly, iw = ow0 - PAD + lx;
        bool ok = (ih >= 0) & (ih < Hin) & (iw >= 0) & (iw < Win);
        #pragma unroll
        for (int ci = 0; ci < 4; ++ci) {
            float x = 0.f, c = 0.f;
            if (ok) {
                size_t idx = ((size_t)(b * 4 + ci)) * planeD + (size_t)ih * Win + iw;
                x = xd[idx]; c = cd[idx];
            }
            sd[UP_FIRST ? ci + 4 : ci][ly][lx] = make_float2(c, x * c);
        }
        #pragma unroll
        for (int ci = 0; ci < 4; ++ci) {
            float x = 0.f, c = 0.f;
            if (ok) {
                size_t idx = ((size_t)(b * 4 + ci)) * planeU + (size_t)(ih >> 1) * Wu + (iw >> 1);
                x = xu[idx]; c = cu[idx];
            }
            sd[UP_FIRST ? ci : ci + 4][ly][lx] = make_float2(c, x * c);
        }
    }
    wsum4(s_w4, 72, tid, &s_sum);
    __syncthreads();

    const int oh = oh0 + threadIdx.y, ow = ow0 + threadIdx.x;
    if (oh >= Hout || ow >= Wout) return;
    const int ty = threadIdx.y, tx = threadIdx.x;

    float nom[4] = {}, den[4] = {};
    #pragma unroll 1
    for (int ci = 0; ci < 8; ++ci) {
        #pragma unroll
        for (int kj = 0; kj < 3; ++kj)
        #pragma unroll
        for (int ki = 0; ki < 3; ++ki) {
            float2 v = sd[ci][ty + kj][tx + ki];
            float4 w = s_w4[ci * 9 + kj * 3 + ki];
            NC_TAP(w, v)
        }
    }
    size_t planeO = (size_t)Hout * Wout;
    NC_EPILOGUE(planeO, Wout)
}

// ---------------------------------------------------------------------------
// 3x3 normalized conv, 4->4, pad=1 (w65). In-dims == out-dims (478x638).
// ---------------------------------------------------------------------------
__global__ __launch_bounds__(256) void nconv3p(
    const float* __restrict__ xin, const float* __restrict__ cin,
    const float* __restrict__ wraw, const float* __restrict__ braw,
    float* __restrict__ xout, float* __restrict__ cout,
    int Hh, int Ww)
{
    const int LT = 18;
    __shared__ float2 sd[4][LT][LT + 1];
    __shared__ float4 s_w4[36];
    __shared__ float4 s_sum, s_bias;

    const int b   = blockIdx.z;
    const int oh0 = blockIdx.y * 16, ow0 = blockIdx.x * 16;
    const int tid = threadIdx.y * 16 + threadIdx.x;

    if (tid < 36) {
        float4 w;
        w.x = softplusf(wraw[0 * 36 + tid]);
        w.y = softplusf(wraw[1 * 36 + tid]);
        w.z = softplusf(wraw[2 * 36 + tid]);
        w.w = softplusf(wraw[3 * 36 + tid]);
        s_w4[tid] = w;
    }
    if (tid == 0) s_bias = make_float4(braw[0], braw[1], braw[2], braw[3]);
    __syncthreads();

    const size_t plane = (size_t)Hh * Ww;
    for (int i = tid; i < LT * LT; i += 256) {
        int ly = i / LT, lx = i - ly * LT;
        int ih = oh0 - 1 + ly, iw = ow0 - 1 + lx;
        bool ok = (ih >= 0) & (ih < Hh) & (iw >= 0) & (iw < Ww);
        #pragma unroll
        for (int ci = 0; ci < 4; ++ci) {
            float x = 0.f, c = 0.f;
            if (ok) {
                size_t idx = ((size_t)(b * 4 + ci)) * plane + (size_t)ih * Ww + iw;
                x = xin[idx]; c = cin[idx];
            }
            sd[ci][ly][lx] = make_float2(c, x * c);
        }
    }
    wsum4(s_w4, 36, tid, &s_sum);
    __syncthreads();

    const int oh = oh0 + threadIdx.y, ow = ow0 + threadIdx.x;
    if (oh >= Hh || ow >= Ww) return;
    const int ty = threadIdx.y, tx = threadIdx.x;

    float nom[4] = {}, den[4] = {};
    #pragma unroll 1
    for (int ci = 0; ci < 4; ++ci) {
        #pragma unroll
        for (int kj = 0; kj < 3; ++kj)
        #pragma unroll
        for (int ki = 0; ki < 3; ++ki) {
            float2 v = sd[ci][ty + kj][tx + ki];
            float4 w = s_w4[ci * 9 + kj * 3 + ki];
            NC_TAP(w, v)
        }
    }
    NC_EPILOGUE(plane, Ww)
}

// ---------------------------------------------------------------------------
// Fused: 1x1 nconv 4->1 (w7) on (478,638) + adaptive avg pool -> (480,640).
// ---------------------------------------------------------------------------
__global__ __launch_bounds__(256) void finalk(
    const float* __restrict__ x, const float* __restrict__ c,
    const float* __restrict__ w7, const float* __restrict__ b7,
    float* __restrict__ out)
{
    __shared__ float sw[5];
    if (threadIdx.x < 4) sw[threadIdx.x] = softplusf(w7[threadIdx.x]);
    if (threadIdx.x == 4) sw[4] = b7[0];
    __syncthreads();

    const int HI = 478, WI = 638, HO = 480, WO = 640;
    int total = 8 * HO * WO;
    int i = blockIdx.x * 256 + threadIdx.x;
    if (i >= total) return;
    int ow = i % WO;
    int oh = (i / WO) % HO;
    int b  = i / (WO * HO);
    float w0 = sw[0], w1 = sw[1], w2 = sw[2], w3 = sw[3], bias = sw[4];

    int sh = (oh * HI) / HO, eh = ((oh + 1) * HI + HO - 1) / HO;
    int sw_ = (ow * WI) / WO, ew = ((ow + 1) * WI + WO - 1) / WO;
    const size_t plane = (size_t)HI * WI;
    float s = 0.f;
    for (int ih = sh; ih < eh; ++ih)
        for (int iw = sw_; iw < ew; ++iw) {
            size_t base = (size_t)b * 4 * plane + (size_t)ih * WI + iw;
            float cc0 = c[base + 0 * plane], cc1 = c[base + 1 * plane],
                  cc2 = c[base + 2 * plane], cc3 = c[base + 3 * plane];
            float nom = w0 * x[base + 0 * plane] * cc0 + w1 * x[base + 1 * plane] * cc1
                      + w2 * x[base + 2 * plane] * cc2 + w3 * x[base + 3 * plane] * cc3;
            float den = w0 * cc0 + w1 * cc1 + w2 * cc2 + w3 * cc3;
            s += nom * rcpf(den + EPSN) + bias;
        }
    out[i] = s * rcpf((float)((eh - sh) * (ew - sw_)));
}

// ---------------------------------------------------------------------------
extern "C" void kernel_launch(void* const* d_in, const int* in_sizes, int n_in,
                              void* d_out, int out_size, void* d_ws, size_t ws_size,
                              hipStream_t stream)
{
    const float* S   = (const float*)d_in[1];
    const float* w1  = (const float*)d_in[3];  const float* b1  = (const float*)d_in[4];
    const float* w2  = (const float*)d_in[5];  const float* b2  = (const float*)d_in[6];
    const float* w3  = (const float*)d_in[7];  const float* b3  = (const float*)d_in[8];
    const float* w4  = (const float*)d_in[9];  const float* b4  = (const float*)d_in[10];
    const float* w5  = (const float*)d_in[11]; const float* b5  = (const float*)d_in[12];
    const float* w6  = (const float*)d_in[13]; const float* b6  = (const float*)d_in[14];
    const float* w65 = (const float*)d_in[15]; const float* b65 = (const float*)d_in[16];
    const float* w7  = (const float*)d_in[17]; const float* b7  = (const float*)d_in[18];
    float* out = (float*)d_out;
    float* ws  = (float*)d_ws;

    const size_t FULL = 9830400, HALF = 2457600, QUAR = 614400, EIGH = 153600;
    float *A0 = ws,        *A1 = A0 + FULL, *A2 = A1 + FULL, *A3 = A2 + FULL;
    float *P0 = A3 + FULL, *P1 = P0 + HALF, *P2 = P1 + HALF, *P3 = P2 + HALF;
    float *Q0 = P3 + HALF, *Q1 = Q0 + QUAR, *Q2 = Q1 + QUAR, *Q3 = Q2 + QUAR;
    float *E0 = Q3 + QUAR, *E1 = E0 + EIGH, *E2 = E1 + EIGH, *E3 = E2 + EIGH;

    dim3 blk(16, 16);
    auto grd = [](int Ho, int Wo) { return dim3((Wo + 15) / 16, (Ho + 15) / 16, 8); };

    // encoder, full res
    nconv5<1, true ><<<grd(480, 640), blk, 0, stream>>>(S,  S,  w1, b1, A0, A1, 480, 640);
    nconv5<4, false><<<grd(480, 640), blk, 0, stream>>>(A0, A1, w2, b2, A2, A3, 480, 640);
    nconv5<4, false><<<grd(480, 640), blk, 0, stream>>>(A2, A3, w3, b3, A0, A1, 480, 640);
    // 1/2 scale
    pool2k<<<(8 * 4 * 240 * 320 + 255) / 256, 256, 0, stream>>>(A0, A1, P0, P1, 480, 640);
    nconv5<4, false><<<grd(240, 320), blk, 0, stream>>>(P0, P1, w2, b2, P2, P3, 240, 320);
    nconv5<4, false><<<grd(240, 320), blk, 0, stream>>>(P2, P3, w3, b3, P0, P1, 240, 320); // x2_ds
    // 1/4 scale
    pool2k<<<(8 * 4 * 120 * 160 + 255) / 256, 256, 0, stream>>>(P0, P1, Q0, Q1, 240, 320);
    nconv5<4, false><<<grd(120, 160), blk, 0, stream>>>(Q0, Q1, w2, b2, Q2, Q3, 120, 160); // x3_ds
    // 1/8 scale
    pool2k<<<(8 * 4 * 60 * 80 + 255) / 256, 256, 0, stream>>>(Q2, Q3, E0, E1, 120, 160);
    nconv5<4, false><<<grd(60, 80), blk, 0, stream>>>(E0, E1, w2, b2, E2, E3, 60, 80);     // x4_ds
    // decoder
    nconv3cat<false, 1><<<grd(120, 160), blk, 0, stream>>>(Q2, Q3, E2, E3, w4, b4, Q0, Q1, 120, 160);
    nconv3cat<false, 1><<<grd(240, 320), blk, 0, stream>>>(P0, P1, Q0, Q1, w5, b5, P2, P3, 240, 320);
    nconv3cat<true , 0><<<grd(478, 638), blk, 0, stream>>>(A0, A1, P2, P3, w6, b6, A2, A3, 480, 640);
    nconv3p<<<grd(478, 638), blk, 0, stream>>>(A2, A3, w65, b65, A0, A1, 478, 638);
    finalk<<<(8 * 480 * 640 + 255) / 256, 256, 0, stream>>>(A0, A1, w7, b7, out);
}

// Round 6
// 403.948 us; speedup vs baseline: 28.1821x; 1.3684x over previous
//
#include <hip/hip_runtime.h>

// NConv depth-completion net, fp32. R6 = R5 +:
// - channel-packed float4 global layout for ALL intermediates (x4 / c4 tensors)
//   -> staging 2xb128 loads, epilogue 2xb128 stores per px (was 8+8 scalars)
// - 2-px/thread x-blocking (32x16 tile) with PARITY-SPLIT LDS (even/odd staged
//   cols in separate arrays) so tap reads stay at 8B lane stride (2-way free).
// - decoder up-source staged at native half-res (cat LDS 41.5->28 KB)
// - keep: #pragma unroll 1 on ci loop (R4: full unroll -> 256 VGPR + spills),
//   no launch_bounds minwaves (R2: forced VGPR cap -> spills).

#define EPSN 1e-20f

__device__ __forceinline__ float softplusf(float x) {
    // matches jax.nn.softplus = max(x,0) + log1p(exp(-|x|))
    return fmaxf(x, 0.f) + log1pf(expf(-fabsf(x)));
}
__device__ __forceinline__ float rcpf(float x) { return __builtin_amdgcn_rcpf(x); }

// Sum s_w4[0..n) across wave 0; lane 0 writes *dst. Needs __syncthreads after.
__device__ __forceinline__ void wsum4(const float4* s_w4, int n, int tid, float4* dst)
{
    if (tid < 64) {
        float4 a = make_float4(0.f, 0.f, 0.f, 0.f);
        for (int i = tid; i < n; i += 64) {
            float4 w = s_w4[i];
            a.x += w.x; a.y += w.y; a.z += w.z; a.w += w.w;
        }
        #pragma unroll
        for (int off = 32; off; off >>= 1) {
            a.x += __shfl_xor(a.x, off);
            a.y += __shfl_xor(a.y, off);
            a.z += __shfl_xor(a.z, off);
            a.w += __shfl_xor(a.w, off);
        }
        if (tid == 0) *dst = a;
    }
}

// 16 FMAs: weight pack W applied to pxA tap VA and pxB tap VB, each float2(c,xc)
#define TAP2(W, VA, VB)                                                     \
    nA[0]=fmaf((W).x,(VA).y,nA[0]); dA[0]=fmaf((W).x,(VA).x,dA[0]);         \
    nA[1]=fmaf((W).y,(VA).y,nA[1]); dA[1]=fmaf((W).y,(VA).x,dA[1]);         \
    nA[2]=fmaf((W).z,(VA).y,nA[2]); dA[2]=fmaf((W).z,(VA).x,dA[2]);         \
    nA[3]=fmaf((W).w,(VA).y,nA[3]); dA[3]=fmaf((W).w,(VA).x,dA[3]);         \
    nB[0]=fmaf((W).x,(VB).y,nB[0]); dB[0]=fmaf((W).x,(VB).x,dB[0]);         \
    nB[1]=fmaf((W).y,(VB).y,nB[1]); dB[1]=fmaf((W).y,(VB).x,dB[1]);         \
    nB[2]=fmaf((W).z,(VB).y,nB[2]); dB[2]=fmaf((W).z,(VB).x,dB[2]);         \
    nB[3]=fmaf((W).w,(VB).y,nB[3]); dB[3]=fmaf((W).w,(VB).x,dB[3]);

// Packed epilogue: 2 px, b128 stores.
#define NC_STORE_PACKED(HOUT, WOUT)                                         \
    {                                                                       \
        const int oh = oh0 + ty, ow = ow0 + 2 * tx;                         \
        if (oh < (HOUT) && ow < (WOUT)) {                                   \
            float4 bias = s_bias, ssum = s_sum;                             \
            float rs0=rcpf(ssum.x), rs1=rcpf(ssum.y),                       \
                  rs2=rcpf(ssum.z), rs3=rcpf(ssum.w);                       \
            size_t t = ((size_t)b * (HOUT) + oh) * (WOUT) + ow;             \
            float4 xo, co;                                                  \
            xo.x = nA[0]*rcpf(dA[0]+EPSN)+bias.x; co.x = dA[0]*rs0;         \
            xo.y = nA[1]*rcpf(dA[1]+EPSN)+bias.y; co.y = dA[1]*rs1;         \
            xo.z = nA[2]*rcpf(dA[2]+EPSN)+bias.z; co.z = dA[2]*rs2;         \
            xo.w = nA[3]*rcpf(dA[3]+EPSN)+bias.w; co.w = dA[3]*rs3;         \
            xout4[t] = xo; cout4[t] = co;                                   \
            if (ow + 1 < (WOUT)) {                                          \
                xo.x = nB[0]*rcpf(dB[0]+EPSN)+bias.x; co.x = dB[0]*rs0;     \
                xo.y = nB[1]*rcpf(dB[1]+EPSN)+bias.y; co.y = dB[1]*rs1;     \
                xo.z = nB[2]*rcpf(dB[2]+EPSN)+bias.z; co.z = dB[2]*rs2;     \
                xo.w = nB[3]*rcpf(dB[3]+EPSN)+bias.w; co.w = dB[3]*rs3;     \
                xout4[t+1] = xo; cout4[t+1] = co;                           \
            }                                                               \
        }                                                                   \
    }

// ---------------------------------------------------------------------------
// First 5x5 nconv: planar S in (c0 = S>0.01 on the fly), packed out. 32x16.
// ---------------------------------------------------------------------------
__global__ __launch_bounds__(256) void nconv5_first(
    const float* __restrict__ S,
    const float* __restrict__ wraw, const float* __restrict__ braw,
    float4* __restrict__ xout4, float4* __restrict__ cout4,
    int Hh, int Ww)
{
    __shared__ float2 sdE[20][19], sdO[20][19];
    __shared__ float4 s_w4[25];
    __shared__ float4 s_sum, s_bias;
    const int b = blockIdx.z;
    const int oh0 = blockIdx.y * 16, ow0 = blockIdx.x * 32;
    const int tx = threadIdx.x, ty = threadIdx.y, tid = ty * 16 + tx;

    if (tid < 25) {
        float4 w;
        w.x = softplusf(wraw[tid]);      w.y = softplusf(wraw[25 + tid]);
        w.z = softplusf(wraw[50 + tid]); w.w = softplusf(wraw[75 + tid]);
        s_w4[tid] = w;
    }
    if (tid == 0) s_bias = make_float4(braw[0], braw[1], braw[2], braw[3]);
    __syncthreads();

    for (int i = tid; i < 20 * 18; i += 256) {
        int ly = i / 18, j = i - ly * 18;
        int ih = oh0 - 2 + ly, iw = ow0 - 2 + 2 * j;   // iw even
        float s0 = 0.f, s1 = 0.f;
        if ((unsigned)ih < (unsigned)Hh && iw >= 0 && iw < Ww - 1) {
            float2 t = *(const float2*)&S[((size_t)b * Hh + ih) * Ww + iw];
            s0 = t.x; s1 = t.y;
        }
        float c0 = (s0 > 0.01f) ? 1.f : 0.f;
        float c1 = (s1 > 0.01f) ? 1.f : 0.f;
        sdE[ly][j] = make_float2(c0, s0 * c0);
        sdO[ly][j] = make_float2(c1, s1 * c1);
    }
    wsum4(s_w4, 25, tid, &s_sum);
    __syncthreads();

    float nA[4] = {}, dA[4] = {}, nB[4] = {}, dB[4] = {};
    #pragma unroll
    for (int kj = 0; kj < 5; ++kj) {
        const float2* rE = &sdE[ty + kj][tx];
        const float2* rO = &sdO[ty + kj][tx];
        float2 e0 = rE[0], o0 = rO[0], e1 = rE[1], o1 = rO[1], e2 = rE[2], o2 = rO[2];
        const float4* wr = &s_w4[kj * 5];
        float4 w;
        w = wr[0]; TAP2(w, e0, o0)
        w = wr[1]; TAP2(w, o0, e1)
        w = wr[2]; TAP2(w, e1, o1)
        w = wr[3]; TAP2(w, o1, e2)
        w = wr[4]; TAP2(w, e2, o2)
    }
    NC_STORE_PACKED(Hh, Ww)
}

// ---------------------------------------------------------------------------
// 5x5 nconv, CI=4, packed in/out. 32x16 tile, 2 px/thread, parity LDS.
// ---------------------------------------------------------------------------
__global__ __launch_bounds__(256) void nconv5p4(
    const float4* __restrict__ xin4, const float4* __restrict__ cin4,
    const float* __restrict__ wraw, const float* __restrict__ braw,
    float4* __restrict__ xout4, float4* __restrict__ cout4,
    int Hh, int Ww)
{
    __shared__ float2 sdE[4][20][19], sdO[4][20][19];
    __shared__ float4 s_w4[100];
    __shared__ float4 s_sum, s_bias;
    const int b = blockIdx.z;
    const int oh0 = blockIdx.y * 16, ow0 = blockIdx.x * 32;
    const int tx = threadIdx.x, ty = threadIdx.y, tid = ty * 16 + tx;

    if (tid < 100) {
        float4 w;
        w.x = softplusf(wraw[tid]);       w.y = softplusf(wraw[100 + tid]);
        w.z = softplusf(wraw[200 + tid]); w.w = softplusf(wraw[300 + tid]);
        s_w4[tid] = w;
    }
    if (tid == 0) s_bias = make_float4(braw[0], braw[1], braw[2], braw[3]);
    __syncthreads();

    const float4 z = make_float4(0.f, 0.f, 0.f, 0.f);
    for (int i = tid; i < 20 * 18; i += 256) {
        int ly = i / 18, j = i - ly * 18;
        int ih = oh0 - 2 + ly, iw = ow0 - 2 + 2 * j;
        float4 cA = z, xA = z, cB = z, xB = z;
        if ((unsigned)ih < (unsigned)Hh) {
            size_t rb = ((size_t)b * Hh + ih) * Ww;
            if ((unsigned)iw < (unsigned)Ww)       { cA = cin4[rb + iw];     xA = xin4[rb + iw]; }
            if ((unsigned)(iw + 1) < (unsigned)Ww) { cB = cin4[rb + iw + 1]; xB = xin4[rb + iw + 1]; }
        }
        sdE[0][ly][j] = make_float2(cA.x, xA.x * cA.x);
        sdE[1][ly][j] = make_float2(cA.y, xA.y * cA.y);
        sdE[2][ly][j] = make_float2(cA.z, xA.z * cA.z);
        sdE[3][ly][j] = make_float2(cA.w, xA.w * cA.w);
        sdO[0][ly][j] = make_float2(cB.x, xB.x * cB.x);
        sdO[1][ly][j] = make_float2(cB.y, xB.y * cB.y);
        sdO[2][ly][j] = make_float2(cB.z, xB.z * cB.z);
        sdO[3][ly][j] = make_float2(cB.w, xB.w * cB.w);
    }
    wsum4(s_w4, 100, tid, &s_sum);
    __syncthreads();

    float nA[4] = {}, dA[4] = {}, nB[4] = {}, dB[4] = {};
    #pragma unroll 1
    for (int ci = 0; ci < 4; ++ci) {
        #pragma unroll
        for (int kj = 0; kj < 5; ++kj) {
            const float2* rE = &sdE[ci][ty + kj][tx];
            const float2* rO = &sdO[ci][ty + kj][tx];
            float2 e0 = rE[0], o0 = rO[0], e1 = rE[1], o1 = rO[1], e2 = rE[2], o2 = rO[2];
            const float4* wr = &s_w4[ci * 25 + kj * 5];
            float4 w;
            w = wr[0]; TAP2(w, e0, o0)
            w = wr[1]; TAP2(w, o0, e1)
            w = wr[2]; TAP2(w, e1, o1)
            w = wr[3]; TAP2(w, o1, e2)
            w = wr[4]; TAP2(w, e2, o2)
        }
    }
    NC_STORE_PACKED(Hh, Ww)
}

// ---------------------------------------------------------------------------
// 2x2 argmax-of-confidence pool, packed: all 4 channels per thread.
// ---------------------------------------------------------------------------
__global__ __launch_bounds__(256) void pool2k(
    const float4* __restrict__ x4, const float4* __restrict__ c4,
    float4* __restrict__ xo4, float4* __restrict__ co4, int Hh, int Ww)
{
    int H2 = Hh / 2, W2 = Ww / 2;
    int total = 8 * H2 * W2;
    int i = blockIdx.x * 256 + threadIdx.x;
    if (i >= total) return;
    int ow = i % W2;
    int oh = (i / W2) % H2;
    int b  = i / (W2 * H2);
    size_t r0 = ((size_t)b * Hh + 2 * oh) * Ww + 2 * ow;
    size_t r1 = r0 + Ww;
    float4 c00 = c4[r0], c01 = c4[r0 + 1], c10 = c4[r1], c11 = c4[r1 + 1];
    float4 x00 = x4[r0], x01 = x4[r0 + 1], x10 = x4[r1], x11 = x4[r1 + 1];
    float4 cm, xm;
    // first-max tie rule, order (0,0),(0,1),(1,0),(1,1)  [strict > keeps first]
    cm.x = c00.x; xm.x = x00.x;
    if (c01.x > cm.x) { cm.x = c01.x; xm.x = x01.x; }
    if (c10.x > cm.x) { cm.x = c10.x; xm.x = x10.x; }
    if (c11.x > cm.x) { cm.x = c11.x; xm.x = x11.x; }
    cm.y = c00.y; xm.y = x00.y;
    if (c01.y > cm.y) { cm.y = c01.y; xm.y = x01.y; }
    if (c10.y > cm.y) { cm.y = c10.y; xm.y = x10.y; }
    if (c11.y > cm.y) { cm.y = c11.y; xm.y = x11.y; }
    cm.z = c00.z; xm.z = x00.z;
    if (c01.z > cm.z) { cm.z = c01.z; xm.z = x01.z; }
    if (c10.z > cm.z) { cm.z = c10.z; xm.z = x10.z; }
    if (c11.z > cm.z) { cm.z = c11.z; xm.z = x11.z; }
    cm.w = c00.w; xm.w = x00.w;
    if (c01.w > cm.w) { cm.w = c01.w; xm.w = x01.w; }
    if (c10.w > cm.w) { cm.w = c10.w; xm.w = x10.w; }
    if (c11.w > cm.w) { cm.w = c11.w; xm.w = x11.w; }
    size_t o = ((size_t)b * H2 + oh) * W2 + ow;
    xo4[o] = xm;
    cm.x *= 0.25f; cm.y *= 0.25f; cm.z *= 0.25f; cm.w *= 0.25f;
    co4[o] = cm;
}

// ---------------------------------------------------------------------------
// 3x3 nconv over concat{direct 4ch (Hin,Win), nearest-2x-up 4ch (Hin/2,Win/2)}.
// Up staged at native half-res. 32x16 tile, 2 px/thread, parity LDS (direct).
// UP_FIRST: up occupies weight channels 0-3 (w6) else 4-7 (w4,w5).
// ---------------------------------------------------------------------------
template<bool UP_FIRST, int PAD>
__global__ __launch_bounds__(256) void nconv3cat(
    const float4* __restrict__ xd4, const float4* __restrict__ cd4,
    const float4* __restrict__ xu4, const float4* __restrict__ cu4,
    const float* __restrict__ wraw, const float* __restrict__ braw,
    float4* __restrict__ xout4, float4* __restrict__ cout4,
    int Hin, int Win)
{
    __shared__ float2 sdE[4][18][18], sdO[4][18][18];   // direct, parity cols
    __shared__ float2 sup[4][10][19];                   // up, native half-res
    __shared__ float4 s_w4[72];
    __shared__ float4 s_sum, s_bias;

    const int Hout = Hin - 2 + 2 * PAD, Wout = Win - 2 + 2 * PAD;
    const int Hu = Hin / 2, Wu = Win / 2;
    const int b = blockIdx.z;
    const int oh0 = blockIdx.y * 16, ow0 = blockIdx.x * 32;
    const int tx = threadIdx.x, ty = threadIdx.y, tid = ty * 16 + tx;

    if (tid < 72) {
        float4 w;
        w.x = softplusf(wraw[tid]);       w.y = softplusf(wraw[72 + tid]);
        w.z = softplusf(wraw[144 + tid]); w.w = softplusf(wraw[216 + tid]);
        s_w4[tid] = w;
    }
    if (tid == 0) s_bias = make_float4(braw[0], braw[1], braw[2], braw[3]);
    __syncthreads();

    const float4 z = make_float4(0.f, 0.f, 0.f, 0.f);
    for (int i = tid; i < 18 * 17; i += 256) {          // direct: 18 rows x 17 pairs
        int ly = i / 17, j = i - ly * 17;
        int ih = oh0 - PAD + ly, iw = ow0 - PAD + 2 * j;
        float4 cA = z, xA = z, cB = z, xB = z;
        if ((unsigned)ih < (unsigned)Hin) {
            size_t rb = ((size_t)b * Hin + ih) * Win;
            if ((unsigned)iw < (unsigned)Win)       { cA = cd4[rb + iw];     xA = xd4[rb + iw]; }
            if ((unsigned)(iw + 1) < (unsigned)Win) { cB = cd4[rb + iw + 1]; xB = xd4[rb + iw + 1]; }
        }
        sdE[0][ly][j] = make_float2(cA.x, xA.x * cA.x);
        sdE[1][ly][j] = make_float2(cA.y, xA.y * cA.y);
        sdE[2][ly][j] = make_float2(cA.z, xA.z * cA.z);
        sdE[3][ly][j] = make_float2(cA.w, xA.w * cA.w);
        sdO[0][ly][j] = make_float2(cB.x, xB.x * cB.x);
        sdO[1][ly][j] = make_float2(cB.y, xB.y * cB.y);
        sdO[2][ly][j] = make_float2(cB.z, xB.z * cB.z);
        sdO[3][ly][j] = make_float2(cB.w, xB.w * cB.w);
    }
    const int ru0 = (oh0 - PAD) >> 1, cu0 = (ow0 - PAD) >> 1;
    for (int i = tid; i < 10 * 18; i += 256) {          // up: 10 rows x 18 cols
        int r = i / 18, k = i - r * 18;
        int ur = ru0 + r, uc = cu0 + k;
        float4 cU = z, xU = z;
        if ((unsigned)ur < (unsigned)Hu && (unsigned)uc < (unsigned)Wu) {
            size_t t = ((size_t)b * Hu + ur) * Wu + uc;
            cU = cu4[t]; xU = xu4[t];
        }
        sup[0][r][k] = make_float2(cU.x, xU.x * cU.x);
        sup[1][r][k] = make_float2(cU.y, xU.y * cU.y);
        sup[2][r][k] = make_float2(cU.z, xU.z * cU.z);
        sup[3][r][k] = make_float2(cU.w, xU.w * cU.w);
    }
    wsum4(s_w4, 72, tid, &s_sum);
    __syncthreads();

    float nA[4] = {}, dA[4] = {}, nB[4] = {}, dB[4] = {};
    #pragma unroll 1
    for (int ci = 0; ci < 4; ++ci) {
        const int chD = UP_FIRST ? ci + 4 : ci;
        const int chU = UP_FIRST ? ci : ci + 4;
        #pragma unroll
        for (int kj = 0; kj < 3; ++kj) {
            const float2* rE = &sdE[ci][ty + kj][tx];
            const float2* rO = &sdO[ci][ty + kj][tx];
            float2 e0 = rE[0], o0 = rO[0], e1 = rE[1], o1 = rO[1];
            const float4* wr = &s_w4[chD * 9 + kj * 3];
            float4 w;
            w = wr[0]; TAP2(w, e0, o0)
            w = wr[1]; TAP2(w, o0, e1)
            w = wr[2]; TAP2(w, e1, o1)
        }
        #pragma unroll
        for (int kj = 0; kj < 3; ++kj) {
            int lyu = (ty + kj + PAD) >> 1;
            const float2* ru = &sup[ci][lyu][tx];
            float2 u0 = ru[0], u1 = ru[1];
            float2 q0, q1, q2, q3;
            if (PAD == 1) {
                float2 u2 = ru[2];
                q0 = u0; q1 = u1; q2 = u1; q3 = u2;   // idx = (m+1)>>1 for m=0..3
            } else {
                q0 = u0; q1 = u0; q2 = u1; q3 = u1;   // idx = m>>1
            }
            const float4* wr = &s_w4[chU * 9 + kj * 3];
            float4 w;
            w = wr[0]; TAP2(w, q0, q1)
            w = wr[1]; TAP2(w, q1, q2)
            w = wr[2]; TAP2(w, q2, q3)
        }
    }
    NC_STORE_PACKED(Hout, Wout)
}

// ---------------------------------------------------------------------------
// 3x3 nconv, 4->4, pad=1 (w65), packed. 32x16 tile, 2 px/thread, parity LDS.
// ---------------------------------------------------------------------------
__global__ __launch_bounds__(256) void nconv3p(
    const float4* __restrict__ xin4, const float4* __restrict__ cin4,
    const float* __restrict__ wraw, const float* __restrict__ braw,
    float4* __restrict__ xout4, float4* __restrict__ cout4,
    int Hh, int Ww)
{
    __shared__ float2 sdE[4][18][18], sdO[4][18][18];
    __shared__ float4 s_w4[36];
    __shared__ float4 s_sum, s_bias;
    const int b = blockIdx.z;
    const int oh0 = blockIdx.y * 16, ow0 = blockIdx.x * 32;
    const int tx = threadIdx.x, ty = threadIdx.y, tid = ty * 16 + tx;

    if (tid < 36) {
        float4 w;
        w.x = softplusf(wraw[tid]);      w.y = softplusf(wraw[36 + tid]);
        w.z = softplusf(wraw[72 + tid]); w.w = softplusf(wraw[108 + tid]);
        s_w4[tid] = w;
    }
    if (tid == 0) s_bias = make_float4(braw[0], braw[1], braw[2], braw[3]);
    __syncthreads();

    const float4 z = make_float4(0.f, 0.f, 0.f, 0.f);
    for (int i = tid; i < 18 * 17; i += 256) {
        int ly = i / 17, j = i - ly * 17;
        int ih = oh0 - 1 + ly, iw = ow0 - 1 + 2 * j;
        float4 cA = z, xA = z, cB = z, xB = z;
        if ((unsigned)ih < (unsigned)Hh) {
            size_t rb = ((size_t)b * Hh + ih) * Ww;
            if ((unsigned)iw < (unsigned)Ww)       { cA = cin4[rb + iw];     xA = xin4[rb + iw]; }
            if ((unsigned)(iw + 1) < (unsigned)Ww) { cB = cin4[rb + iw + 1]; xB = xin4[rb + iw + 1]; }
        }
        sdE[0][ly][j] = make_float2(cA.x, xA.x * cA.x);
        sdE[1][ly][j] = make_float2(cA.y, xA.y * cA.y);
        sdE[2][ly][j] = make_float2(cA.z, xA.z * cA.z);
        sdE[3][ly][j] = make_float2(cA.w, xA.w * cA.w);
        sdO[0][ly][j] = make_float2(cB.x, xB.x * cB.x);
        sdO[1][ly][j] = make_float2(cB.y, xB.y * cB.y);
        sdO[2][ly][j] = make_float2(cB.z, xB.z * cB.z);
        sdO[3][ly][j] = make_float2(cB.w, xB.w * cB.w);
    }
    wsum4(s_w4, 36, tid, &s_sum);
    __syncthreads();

    float nA[4] = {}, dA[4] = {}, nB[4] = {}, dB[4] = {};
    #pragma unroll 1
    for (int ci = 0; ci < 4; ++ci) {
        #pragma unroll
        for (int kj = 0; kj < 3; ++kj) {
            const float2* rE = &sdE[ci][ty + kj][tx];
            const float2* rO = &sdO[ci][ty + kj][tx];
            float2 e0 = rE[0], o0 = rO[0], e1 = rE[1], o1 = rO[1];
            const float4* wr = &s_w4[ci * 9 + kj * 3];
            float4 w;
            w = wr[0]; TAP2(w, e0, o0)
            w = wr[1]; TAP2(w, o0, e1)
            w = wr[2]; TAP2(w, e1, o1)
        }
    }
    NC_STORE_PACKED(Hh, Ww)
}

// ---------------------------------------------------------------------------
// Fused: 1x1 nconv 4->1 (w7) on packed (478,638) + adaptive pool -> (480,640).
// ---------------------------------------------------------------------------
__global__ __launch_bounds__(256) void finalk(
    const float4* __restrict__ x4, const float4* __restrict__ c4,
    const float* __restrict__ w7, const float* __restrict__ b7,
    float* __restrict__ out)
{
    __shared__ float sw[5];
    if (threadIdx.x < 4) sw[threadIdx.x] = softplusf(w7[threadIdx.x]);
    if (threadIdx.x == 4) sw[4] = b7[0];
    __syncthreads();

    const int HI = 478, WI = 638, HO = 480, WO = 640;
    int total = 8 * HO * WO;
    int i = blockIdx.x * 256 + threadIdx.x;
    if (i >= total) return;
    int ow = i % WO;
    int oh = (i / WO) % HO;
    int b  = i / (WO * HO);
    float w0 = sw[0], w1 = sw[1], w2 = sw[2], w3 = sw[3], bias = sw[4];

    int sh = (oh * HI) / HO, eh = ((oh + 1) * HI + HO - 1) / HO;
    int sw_ = (ow * WI) / WO, ew = ((ow + 1) * WI + WO - 1) / WO;
    float s = 0.f;
    for (int ih = sh; ih < eh; ++ih)
        for (int iw = sw_; iw < ew; ++iw) {
            size_t t = ((size_t)b * HI + ih) * WI + iw;
            float4 cc = c4[t], xx = x4[t];
            float den = w0 * cc.x + w1 * cc.y + w2 * cc.z + w3 * cc.w;
            float nomv = w0 * xx.x * cc.x + w1 * xx.y * cc.y
                       + w2 * xx.z * cc.z + w3 * xx.w * cc.w;
            s += nomv * rcpf(den + EPSN) + bias;
        }
    out[i] = s * rcpf((float)((eh - sh) * (ew - sw_)));
}

// ---------------------------------------------------------------------------
extern "C" void kernel_launch(void* const* d_in, const int* in_sizes, int n_in,
                              void* d_out, int out_size, void* d_ws, size_t ws_size,
                              hipStream_t stream)
{
    const float* S   = (const float*)d_in[1];
    const float* w1  = (const float*)d_in[3];  const float* b1  = (const float*)d_in[4];
    const float* w2  = (const float*)d_in[5];  const float* b2  = (const float*)d_in[6];
    const float* w3  = (const float*)d_in[7];  const float* b3  = (const float*)d_in[8];
    const float* w4  = (const float*)d_in[9];  const float* b4  = (const float*)d_in[10];
    const float* w5  = (const float*)d_in[11]; const float* b5  = (const float*)d_in[12];
    const float* w6  = (const float*)d_in[13]; const float* b6  = (const float*)d_in[14];
    const float* w65 = (const float*)d_in[15]; const float* b65 = (const float*)d_in[16];
    const float* w7  = (const float*)d_in[17]; const float* b7  = (const float*)d_in[18];
    float* out = (float*)d_out;
    float* ws  = (float*)d_ws;

    // All intermediates channel-packed: tensor = float4[B*H*W].
    const size_t FULL = 9830400, HALF = 2457600, QUAR = 614400, EIGH = 153600;
    float4 *A0 = (float4*)ws,              *A1 = (float4*)(ws + FULL),
           *A2 = (float4*)(ws + 2*FULL),   *A3 = (float4*)(ws + 3*FULL);
    float4 *P0 = (float4*)(ws + 4*FULL),            *P1 = (float4*)(ws + 4*FULL + HALF),
           *P2 = (float4*)(ws + 4*FULL + 2*HALF),   *P3 = (float4*)(ws + 4*FULL + 3*HALF);
    float4 *Q0 = (float4*)(ws + 4*FULL + 4*HALF),          *Q1 = (float4*)(ws + 4*FULL + 4*HALF + QUAR),
           *Q2 = (float4*)(ws + 4*FULL + 4*HALF + 2*QUAR), *Q3 = (float4*)(ws + 4*FULL + 4*HALF + 3*QUAR);
    float4 *E0 = (float4*)(ws + 4*FULL + 4*HALF + 4*QUAR),
           *E1 = (float4*)(ws + 4*FULL + 4*HALF + 4*QUAR + EIGH),
           *E2 = (float4*)(ws + 4*FULL + 4*HALF + 4*QUAR + 2*EIGH),
           *E3 = (float4*)(ws + 4*FULL + 4*HALF + 4*QUAR + 3*EIGH);

    dim3 blk(16, 16);
    auto grd = [](int Ho, int Wo) { return dim3((Wo + 31) / 32, (Ho + 15) / 16, 8); };

    // encoder, full res (x in even slots, c in odd)
    nconv5_first<<<grd(480, 640), blk, 0, stream>>>(S, w1, b1, A0, A1, 480, 640);
    nconv5p4<<<grd(480, 640), blk, 0, stream>>>(A0, A1, w2, b2, A2, A3, 480, 640);
    nconv5p4<<<grd(480, 640), blk, 0, stream>>>(A2, A3, w3, b3, A0, A1, 480, 640);   // x1,c1
    // 1/2 scale
    pool2k<<<(8 * 240 * 320 + 255) / 256, 256, 0, stream>>>(A0, A1, P0, P1, 480, 640);
    nconv5p4<<<grd(240, 320), blk, 0, stream>>>(P0, P1, w2, b2, P2, P3, 240, 320);
    nconv5p4<<<grd(240, 320), blk, 0, stream>>>(P2, P3, w3, b3, P0, P1, 240, 320);   // x2_ds
    // 1/4 scale
    pool2k<<<(8 * 120 * 160 + 255) / 256, 256, 0, stream>>>(P0, P1, Q0, Q1, 240, 320);
    nconv5p4<<<grd(120, 160), blk, 0, stream>>>(Q0, Q1, w2, b2, Q2, Q3, 120, 160);   // x3_ds
    // 1/8 scale
    pool2k<<<(8 * 60 * 80 + 255) / 256, 256, 0, stream>>>(Q2, Q3, E0, E1, 120, 160);
    nconv5p4<<<grd(60, 80), blk, 0, stream>>>(E0, E1, w2, b2, E2, E3, 60, 80);       // x4_ds
    // decoder
    nconv3cat<false, 1><<<grd(120, 160), blk, 0, stream>>>(Q2, Q3, E2, E3, w4, b4, Q0, Q1, 120, 160);
    nconv3cat<false, 1><<<grd(240, 320), blk, 0, stream>>>(P0, P1, Q0, Q1, w5, b5, P2, P3, 240, 320);
    nconv3cat<true , 0><<<grd(478, 638), blk, 0, stream>>>(A0, A1, P2, P3, w6, b6, A2, A3, 480, 640);
    nconv3p<<<grd(478, 638), blk, 0, stream>>>(A2, A3, w65, b65, A0, A1, 478, 638);
    finalk<<<(8 * 480 * 640 + 255) / 256, 256, 0, stream>>>(A0, A1, w7, b7, out);
}